// Round 7
// baseline (243.448 us; speedup 1.0000x reference)
//
#include <hip/hip_runtime.h>
#include <math.h>

#define S_LEN  4096
#define DMODEL 1024
#define NH     16
#define HD     64

typedef __bf16 bf16;
typedef __attribute__((ext_vector_type(8))) __bf16 bf16x8;
typedef __attribute__((ext_vector_type(4))) __bf16 bf16x4;
typedef __attribute__((ext_vector_type(4))) float  f32x4;

// direct global->LDS, 16B per lane. dest = wave-uniform base + lane*16.
__device__ inline void gl_lds16(const void* g, void* l) {
    __builtin_amdgcn_global_load_lds(
        (const __attribute__((address_space(1))) void*)g,
        (__attribute__((address_space(3))) void*)l, 16, 0, 0);
}

// ---------------------------------------------------------------------------
// fp32 -> bf16 conversion for x, Wq, Wk, Wv, Wo in one launch.
// ---------------------------------------------------------------------------
__global__ __launch_bounds__(256)
void f32_to_bf16_all(const float* __restrict__ x,  const float* __restrict__ wq,
                     const float* __restrict__ wk, const float* __restrict__ wv,
                     const float* __restrict__ wo,
                     bf16* __restrict__ xb,  bf16* __restrict__ wqb,
                     bf16* __restrict__ wkb, bf16* __restrict__ wvb,
                     bf16* __restrict__ wob)
{
    int b = blockIdx.x;
    const float* s; bf16* d; int idx;
    if      (b < 2048) { s = x;  d = xb;  idx = b; }
    else if (b < 2560) { s = wq; d = wqb; idx = b - 2048; }
    else if (b < 3072) { s = wk; d = wkb; idx = b - 2560; }
    else if (b < 3584) { s = wv; d = wvb; idx = b - 3072; }
    else               { s = wo; d = wob; idx = b - 3584; }
    size_t e0 = ((size_t)idx * 256 + threadIdx.x) * 8;
    float4 a = *(const float4*)(s + e0);
    float4 c = *(const float4*)(s + e0 + 4);
    bf16x8 r;
    r[0] = (bf16)a.x; r[1] = (bf16)a.y; r[2] = (bf16)a.z; r[3] = (bf16)a.w;
    r[4] = (bf16)c.x; r[5] = (bf16)c.y; r[6] = (bf16)c.z; r[7] = (bf16)c.w;
    *(bf16x8*)(d + e0) = r;
}

// ---------------------------------------------------------------------------
// bf16 MFMA GEMM, NT: C[m,n] = sum_k A[m,k]*B[n,k].  128x128 tile, BK=32,
// 4 waves, 2-phase LDS double-buffer with global_load_lds(16B).
// ---------------------------------------------------------------------------
template <typename OutT>
__device__ inline void gemm_body(const bf16* __restrict__ A, const bf16* __restrict__ B,
                                 OutT* __restrict__ C, bool trans, int M, int N, int K)
{
    __shared__ __align__(16) bf16 As[2][128 * 32];
    __shared__ __align__(16) bf16 Bs[2][128 * 32];

    const int t = threadIdx.x, lane = t & 63, w = t >> 6;
    const int m0 = blockIdx.x * 128, n0 = blockIdx.y * 128;
    const int wr = (w >> 1) * 64, wc = (w & 1) * 64;
    const int fr = lane & 15, fc = lane >> 4;

    const int  srow = w * 32 + (lane >> 2);
    const int  schk = (lane & 3) * 8;
    const bf16* Ag = A + (size_t)(m0 + srow) * K + schk;
    const bf16* Bg = B + (size_t)(n0 + srow) * K + schk;
    const int  sbase = (w * 32) * 32;

    f32x4 acc[4][4] = {};

    auto stage = [&](int buf, int k0) {
        gl_lds16(Ag + k0,                  &As[buf][sbase]);
        gl_lds16(Ag + k0 + (size_t)16 * K, &As[buf][sbase + 16 * 32]);
        gl_lds16(Bg + k0,                  &Bs[buf][sbase]);
        gl_lds16(Bg + k0 + (size_t)16 * K, &Bs[buf][sbase + 16 * 32]);
    };

    stage(0, 0);
    __syncthreads();
    int cur = 0;
    for (int k0 = 0; k0 < K; k0 += 32) {
        if (k0 + 32 < K) stage(cur ^ 1, k0 + 32);
        bf16x8 af[4], bv[4];
        #pragma unroll
        for (int fm = 0; fm < 4; ++fm)
            af[fm] = *(const bf16x8*)&As[cur][(wr + fm * 16 + fr) * 32 + fc * 8];
        #pragma unroll
        for (int fn = 0; fn < 4; ++fn)
            bv[fn] = *(const bf16x8*)&Bs[cur][(wc + fn * 16 + fr) * 32 + fc * 8];
        #pragma unroll
        for (int fm = 0; fm < 4; ++fm)
            #pragma unroll
            for (int fn = 0; fn < 4; ++fn)
                acc[fm][fn] = __builtin_amdgcn_mfma_f32_16x16x32_bf16(
                                  af[fm], bv[fn], acc[fm][fn], 0, 0, 0);
        __syncthreads();
        cur ^= 1;
    }

    #pragma unroll
    for (int fm = 0; fm < 4; ++fm)
        #pragma unroll
        for (int fn = 0; fn < 4; ++fn)
            #pragma unroll
            for (int r = 0; r < 4; ++r) {
                int row = m0 + wr + fm * 16 + fc * 4 + r;
                int col = n0 + wc + fn * 16 + fr;
                float v = acc[fm][fn][r];
                if (trans) C[(size_t)col * M + row] = (OutT)v;
                else       C[(size_t)row * N + col] = (OutT)v;
            }
}

__global__ __launch_bounds__(256)
void gemm_qkv(const bf16* __restrict__ A,
              const bf16* __restrict__ Wq, const bf16* __restrict__ Wk,
              const bf16* __restrict__ Wv,
              bf16* __restrict__ Qo, bf16* __restrict__ Ko, bf16* __restrict__ Vo)
{
    const int z = blockIdx.z;
    const bf16* B = (z == 0) ? Wq : (z == 1) ? Wk : Wv;
    bf16*       C = (z == 0) ? Qo : (z == 1) ? Ko : Vo;
    gemm_body<bf16>(A, B, C, z == 2, S_LEN, DMODEL, DMODEL);
}

__global__ __launch_bounds__(256)
void gemm_out(const bf16* __restrict__ A, const bf16* __restrict__ B,
              float* __restrict__ C)
{
    gemm_body<float>(A, B, C, false, S_LEN, DMODEL, DMODEL);
}

// ---------------------------------------------------------------------------
// MFMA flash attention, causal, NO-MAX softmax, swapped-operand form,
// PAIR-BLOCK: block (h, j) computes q-tiles {i, 63-i} (i = j<16 ? j : 47-j),
// so every block does exactly 65 tile-computes (uniform — no causal tail),
// and the two q-tiles SHARE K/V staging and K/V fragment reads (one LDS read
// feeds two MFMAs). Grid 512 = 2 blocks/CU steady.
//   S^T = mfma(K,Q): lane holds 16 P values for one q-row -> in-lane softmax,
//   scalar lsum; PV with permuted k-map (k = 8*fc + 4*(fn&1) + r) -> pa built
//   by in-lane cvt (no LDS); V read as 2x ds_read_b64 from swizzled Vs.
// ---------------------------------------------------------------------------
__global__ __launch_bounds__(256)
void attn_mfma(const bf16* __restrict__ Q, const bf16* __restrict__ Kb,
               const bf16* __restrict__ Vt, bf16* __restrict__ O)
{
    __shared__ __align__(16) bf16 Ks[2][64 * 64];   // [kv][hd]  swizzled
    __shared__ __align__(16) bf16 Vs[2][64 * 64];   // [d][kv]   swizzled

    const int t = threadIdx.x, lane = t & 63, w = t >> 6;
    const int h = blockIdx.x & (NH - 1);
    const int j = (int)(blockIdx.x >> 4);            // 0..31
    const int i = (j < 16) ? j : 47 - j;             // CU mates get {i, 31-i}
    const int qiA = i, qiB = 63 - i;
    const int qbA = qiA * 64, qbB = qiB * 64;
    const int fr = lane & 15, fc = lane >> 4;

    // Q fragments for both q-tiles (raw; scale folded into exp2 constant)
    bf16x8 qfA[2], qfB[2];
    #pragma unroll
    for (int kh = 0; kh < 2; ++kh) {
        qfA[kh] = *(const bf16x8*)(Q + (size_t)(qbA + w * 16 + fr) * DMODEL
                                     + h * HD + kh * 32 + fc * 8);
        qfB[kh] = *(const bf16x8*)(Q + (size_t)(qbB + w * 16 + fr) * DMODEL
                                     + h * HD + kh * 32 + fc * 8);
    }

    f32x4 oA[4] = {}, oB[4] = {};
    float lsA = 0.f, lsB = 0.f;

    auto stage = [&](int buf, int kb2) {
        const int kbase2 = kb2 * 64;
        #pragma unroll
        for (int ii = 0; ii < 2; ++ii) {
            int row = w * 16 + ii * 8 + (lane >> 3);
            int gch = (lane & 7) ^ (row & 7);
            gl_lds16(Kb + (size_t)(kbase2 + row) * DMODEL + h * HD + gch * 8,
                     &Ks[buf][(w * 16 + ii * 8) * 64]);
            gl_lds16(Vt + (size_t)(h * HD + row) * S_LEN + kbase2 + gch * 8,
                     &Vs[buf][(w * 16 + ii * 8) * 64]);
        }
    };

    stage(0, 0);
    __syncthreads();

    int cur = 0;
    #pragma unroll 2
    for (int kb = 0; kb <= qiB; ++kb) {
        if (kb < qiB) stage(cur ^ 1, kb + 1);   // prefetch overlaps compute
        const bool actA = (kb <= qiA);

        // ---- S^T = K Q^T for both tiles; K fragment read ONCE ----
        f32x4 sA[4] = {}, sB[4] = {};
        #pragma unroll
        for (int fn = 0; fn < 4; ++fn)
            #pragma unroll
            for (int kh = 0; kh < 2; ++kh) {
                bf16x8 kf = *(const bf16x8*)
                    &Ks[cur][(fn * 16 + fr) * 64 + (((kh * 4 + fc) ^ (fr & 7)) * 8)];
                if (actA)
                    sA[fn] = __builtin_amdgcn_mfma_f32_16x16x32_bf16(kf, qfA[kh], sA[fn], 0, 0, 0);
                sB[fn] = __builtin_amdgcn_mfma_f32_16x16x32_bf16(kf, qfB[kh], sB[fn], 0, 0, 0);
            }

        // ---- causal masks on diagonal tiles (local coords identical) ----
        if (kb == qiA) {
            #pragma unroll
            for (int fn = 0; fn < 4; ++fn)
                #pragma unroll
                for (int r = 0; r < 4; ++r)
                    if (fn * 16 + fc * 4 + r > w * 16 + fr) sA[fn][r] = -INFINITY;
        }
        if (kb == qiB) {
            #pragma unroll
            for (int fn = 0; fn < 4; ++fn)
                #pragma unroll
                for (int r = 0; r < 4; ++r)
                    if (fn * 16 + fc * 4 + r > w * 16 + fr) sB[fn][r] = -INFINITY;
        }

        // ---- p = exp2(S * log2e/8); scalar lsum; pa lane-local ----
        bf16x8 paA[2], paB[2];
        if (actA) {
            #pragma unroll
            for (int fn = 0; fn < 4; ++fn)
                #pragma unroll
                for (int r = 0; r < 4; ++r) {
                    float p = exp2f(sA[fn][r] * 0.18033688011112042f);
                    lsA += p;
                    sA[fn][r] = p;
                }
            #pragma unroll
            for (int kvh = 0; kvh < 2; ++kvh)
                #pragma unroll
                for (int r = 0; r < 4; ++r) {
                    paA[kvh][r]     = (bf16)sA[2 * kvh][r];
                    paA[kvh][4 + r] = (bf16)sA[2 * kvh + 1][r];
                }
        }
        #pragma unroll
        for (int fn = 0; fn < 4; ++fn)
            #pragma unroll
            for (int r = 0; r < 4; ++r) {
                float p = exp2f(sB[fn][r] * 0.18033688011112042f);
                lsB += p;
                sB[fn][r] = p;
            }
        #pragma unroll
        for (int kvh = 0; kvh < 2; ++kvh)
            #pragma unroll
            for (int r = 0; r < 4; ++r) {
                paB[kvh][r]     = (bf16)sB[2 * kvh][r];
                paB[kvh][4 + r] = (bf16)sB[2 * kvh + 1][r];
            }

        // ---- O^T += V P^T; V fragment read ONCE, feeds both tiles ----
        #pragma unroll
        for (int kvh = 0; kvh < 2; ++kvh)
            #pragma unroll
            for (int fd = 0; fd < 4; ++fd) {
                const int rowb = (fd * 16 + fr) * 64 + (fc & 1) * 4;
                bf16x4 va = *(const bf16x4*)
                    &Vs[cur][rowb + (((kvh * 4     + (fc >> 1)) ^ (fr & 7)) * 8)];
                bf16x4 vb = *(const bf16x4*)
                    &Vs[cur][rowb + (((kvh * 4 + 2 + (fc >> 1)) ^ (fr & 7)) * 8)];
                bf16x8 vf;
                #pragma unroll
                for (int e = 0; e < 4; ++e) { vf[e] = va[e]; vf[4 + e] = vb[e]; }
                if (actA)
                    oA[fd] = __builtin_amdgcn_mfma_f32_16x16x32_bf16(vf, paA[kvh], oA[fd], 0, 0, 0);
                oB[fd] = __builtin_amdgcn_mfma_f32_16x16x32_bf16(vf, paB[kvh], oB[fd], 0, 0, 0);
            }

        __syncthreads();   // drains prefetch (vmcnt) + protects LDS bufs
        cur ^= 1;
    }

    // ---- epilogue: reduce lsums across the 4 fc-lanes; store both tiles ----
    lsA += __shfl_xor(lsA, 16, 64);
    lsA += __shfl_xor(lsA, 32, 64);
    lsB += __shfl_xor(lsB, 16, 64);
    lsB += __shfl_xor(lsB, 32, 64);
    const float invA = 1.0f / lsA, invB = 1.0f / lsB;

    #pragma unroll
    for (int fd = 0; fd < 4; ++fd) {
        bf16x4 ovA, ovB;
        #pragma unroll
        for (int r = 0; r < 4; ++r) {
            ovA[r] = (bf16)(oA[fd][r] * invA);
            ovB[r] = (bf16)(oB[fd][r] * invB);
        }
        *(bf16x4*)(O + (size_t)(qbA + w * 16 + fr) * DMODEL
                     + h * HD + fd * 16 + fc * 4) = ovA;
        *(bf16x4*)(O + (size_t)(qbB + w * 16 + fr) * DMODEL
                     + h * HD + fd * 16 + fc * 4) = ovB;
    }
}

// ---------------------------------------------------------------------------
extern "C" void kernel_launch(void* const* d_in, const int* in_sizes, int n_in,
                              void* d_out, int out_size, void* d_ws, size_t ws_size,
                              hipStream_t stream)
{
    const float* x  = (const float*)d_in[0];
    const float* Wq = (const float*)d_in[1];
    const float* Wk = (const float*)d_in[2];
    const float* Wv = (const float*)d_in[3];
    const float* Wo = (const float*)d_in[4];

    const size_t M1 = 1024 * 1024;
    bf16* xb  = (bf16*)d_ws;          // 4M elems
    bf16* wqb = xb  + 4 * M1;         // 1M each
    bf16* wkb = wqb + M1;
    bf16* wvb = wkb + M1;
    bf16* wob = wvb + M1;
    bf16* Qb  = wob + M1;             // 4M
    bf16* Kb  = Qb  + 4 * M1;         // 4M
    bf16* Vt  = Kb  + 4 * M1;         // 4M  (transposed: [DMODEL][S])
    bf16* Ob  = Vt  + 4 * M1;         // 4M

    f32_to_bf16_all<<<4096, 256, 0, stream>>>(x, Wq, Wk, Wv, Wo,
                                              xb, wqb, wkb, wvb, wob);

    gemm_qkv<<<dim3(S_LEN / 128, DMODEL / 128, 3), 256, 0, stream>>>(
        xb, wqb, wkb, wvb, Qb, Kb, Vt);

    attn_mfma<<<dim3((S_LEN / 64) * NH / 2), 256, 0, stream>>>(Qb, Kb, Vt, Ob);

    gemm_out<<<dim3(S_LEN / 128, DMODEL / 128), 256, 0, stream>>>(
        Ob, wob, (float*)d_out);
}

// Round 8
// 223.189 us; speedup vs baseline: 1.0908x; 1.0908x over previous
//
#include <hip/hip_runtime.h>
#include <math.h>

#define S_LEN  4096
#define DMODEL 1024
#define NH     16
#define HD     64

typedef __bf16 bf16;
typedef __attribute__((ext_vector_type(8))) __bf16 bf16x8;
typedef __attribute__((ext_vector_type(4))) __bf16 bf16x4;
typedef __attribute__((ext_vector_type(4))) float  f32x4;

// direct global->LDS, 16B per lane. dest = wave-uniform base + lane*16.
__device__ inline void gl_lds16(const void* g, void* l) {
    __builtin_amdgcn_global_load_lds(
        (const __attribute__((address_space(1))) void*)g,
        (__attribute__((address_space(3))) void*)l, 16, 0, 0);
}

// ---------------------------------------------------------------------------
// fp32 -> bf16 conversion for x, Wq, Wk, Wv, Wo in one launch.
// ---------------------------------------------------------------------------
__global__ __launch_bounds__(256)
void f32_to_bf16_all(const float* __restrict__ x,  const float* __restrict__ wq,
                     const float* __restrict__ wk, const float* __restrict__ wv,
                     const float* __restrict__ wo,
                     bf16* __restrict__ xb,  bf16* __restrict__ wqb,
                     bf16* __restrict__ wkb, bf16* __restrict__ wvb,
                     bf16* __restrict__ wob)
{
    int b = blockIdx.x;
    const float* s; bf16* d; int idx;
    if      (b < 2048) { s = x;  d = xb;  idx = b; }
    else if (b < 2560) { s = wq; d = wqb; idx = b - 2048; }
    else if (b < 3072) { s = wk; d = wkb; idx = b - 2560; }
    else if (b < 3584) { s = wv; d = wvb; idx = b - 3072; }
    else               { s = wo; d = wob; idx = b - 3584; }
    size_t e0 = ((size_t)idx * 256 + threadIdx.x) * 8;
    float4 a = *(const float4*)(s + e0);
    float4 c = *(const float4*)(s + e0 + 4);
    bf16x8 r;
    r[0] = (bf16)a.x; r[1] = (bf16)a.y; r[2] = (bf16)a.z; r[3] = (bf16)a.w;
    r[4] = (bf16)c.x; r[5] = (bf16)c.y; r[6] = (bf16)c.z; r[7] = (bf16)c.w;
    *(bf16x8*)(d + e0) = r;
}

// ---------------------------------------------------------------------------
// bf16 MFMA GEMM, NT: C[m,n] = sum_k A[m,k]*B[n,k].  128x128 tile, BK=32,
// 4 waves, 2-phase LDS double-buffer with global_load_lds(16B).
// LDS XOR-swizzle (T2, rule #21): linear gl_lds dest; SOURCE chunk
// c' = c ^ ((row16>>1)&3); fragment read slot = fc ^ ((fr>>1)&3).
// Unswizzled this layout is an 8-way bank conflict on every ds_read_b128
// (bank-group = (fr&1)*16 + fc*4, 8 rows deep); swizzled it is 2-way (free).
// ---------------------------------------------------------------------------
template <typename OutT>
__device__ inline void gemm_body(const bf16* __restrict__ A, const bf16* __restrict__ B,
                                 OutT* __restrict__ C, bool trans, int M, int N, int K)
{
    __shared__ __align__(16) bf16 As[2][128 * 32];
    __shared__ __align__(16) bf16 Bs[2][128 * 32];

    const int t = threadIdx.x, lane = t & 63, w = t >> 6;
    const int m0 = blockIdx.x * 128, n0 = blockIdx.y * 128;
    const int wr = (w >> 1) * 64, wc = (w & 1) * 64;
    const int fr = lane & 15, fc = lane >> 4;

    // staging: wave w owns rows [w*32, w*32+32). lane -> (row16 = lane>>2,
    // chunk = lane&3); source chunk swizzled: c' = c ^ ((row16>>1)&3).
    const int  srow = w * 32 + (lane >> 2);
    const int  schk = ((lane & 3) ^ ((lane >> 3) & 3)) * 8;
    const bf16* Ag = A + (size_t)(m0 + srow) * K + schk;
    const bf16* Bg = B + (size_t)(n0 + srow) * K + schk;
    const int  sbase = (w * 32) * 32;

    f32x4 acc[4][4] = {};

    auto stage = [&](int buf, int k0) {
        gl_lds16(Ag + k0,                  &As[buf][sbase]);
        gl_lds16(Ag + k0 + (size_t)16 * K, &As[buf][sbase + 16 * 32]);
        gl_lds16(Bg + k0,                  &Bs[buf][sbase]);
        gl_lds16(Bg + k0 + (size_t)16 * K, &Bs[buf][sbase + 16 * 32]);
    };

    // read-side swizzle slot (fm/wr are multiples of 16 -> fm-invariant)
    const int rslot = (fc ^ ((fr >> 1) & 3)) * 8;

    stage(0, 0);
    __syncthreads();
    int cur = 0;
    for (int k0 = 0; k0 < K; k0 += 32) {
        if (k0 + 32 < K) stage(cur ^ 1, k0 + 32);
        bf16x8 af[4], bv[4];
        #pragma unroll
        for (int fm = 0; fm < 4; ++fm)
            af[fm] = *(const bf16x8*)&As[cur][(wr + fm * 16 + fr) * 32 + rslot];
        #pragma unroll
        for (int fn = 0; fn < 4; ++fn)
            bv[fn] = *(const bf16x8*)&Bs[cur][(wc + fn * 16 + fr) * 32 + rslot];
        #pragma unroll
        for (int fm = 0; fm < 4; ++fm)
            #pragma unroll
            for (int fn = 0; fn < 4; ++fn)
                acc[fm][fn] = __builtin_amdgcn_mfma_f32_16x16x32_bf16(
                                  af[fm], bv[fn], acc[fm][fn], 0, 0, 0);
        __syncthreads();
        cur ^= 1;
    }

    #pragma unroll
    for (int fm = 0; fm < 4; ++fm)
        #pragma unroll
        for (int fn = 0; fn < 4; ++fn)
            #pragma unroll
            for (int r = 0; r < 4; ++r) {
                int row = m0 + wr + fm * 16 + fc * 4 + r;
                int col = n0 + wc + fn * 16 + fr;
                float v = acc[fm][fn][r];
                if (trans) C[(size_t)col * M + row] = (OutT)v;
                else       C[(size_t)row * N + col] = (OutT)v;
            }
}

__global__ __launch_bounds__(256)
void gemm_qkv(const bf16* __restrict__ A,
              const bf16* __restrict__ Wq, const bf16* __restrict__ Wk,
              const bf16* __restrict__ Wv,
              bf16* __restrict__ Qo, bf16* __restrict__ Ko, bf16* __restrict__ Vo)
{
    const int z = blockIdx.z;
    const bf16* B = (z == 0) ? Wq : (z == 1) ? Wk : Wv;
    bf16*       C = (z == 0) ? Qo : (z == 1) ? Ko : Vo;
    gemm_body<bf16>(A, B, C, z == 2, S_LEN, DMODEL, DMODEL);
}

__global__ __launch_bounds__(256)
void gemm_out(const bf16* __restrict__ A, const bf16* __restrict__ B,
              float* __restrict__ C)
{
    gemm_body<float>(A, B, C, false, S_LEN, DMODEL, DMODEL);
}

// ---------------------------------------------------------------------------
// MFMA flash attention (R6 version, reverted from the R7 pair-block regress):
// causal, NO-MAX softmax, swapped-operand form.
//   S^T = mfma(K_frag, Q_frag)  -> each lane holds 16 P values for ONE q-row
//     (q = lane&15, kv = fn*16 + (lane>>4)*4 + r) -> softmax fully in-lane,
//     lsum is a single scalar per lane (reduced once in epilogue).
//   PV uses a permuted kv<->k mapping  k = 8*fc + 4*(fn&1) + r  so the P
//     fragment is built by pure in-lane f32->bf16 cvt (NO LDS round-trip).
//   Matching V fragment: two ds_read_b64 per (kvh,fd) from the same swizzled
//     Vs (slot^(row&7)); O^T = mfma(V_frag, P_frag) -> 8B vector stores.
// K/V double-buffered (2-phase), 1 barrier/tile. qi permuted for balance.
// ---------------------------------------------------------------------------
__global__ __launch_bounds__(256)
void attn_mfma(const bf16* __restrict__ Q, const bf16* __restrict__ Kb,
               const bf16* __restrict__ Vt, bf16* __restrict__ O)
{
    __shared__ __align__(16) bf16 Ks[2][64 * 64];   // [kv][hd]  swizzled
    __shared__ __align__(16) bf16 Vs[2][64 * 64];   // [d][kv]   swizzled

    const int t = threadIdx.x, lane = t & 63, w = t >> 6;
    const int h  = blockIdx.x & (NH - 1);
    const int j  = (int)(blockIdx.x >> 4);          // 0..63
    const int a  = j & 15, sg = j >> 4;
    // balanced permutation: stride-16-in-j groups sum to equal causal work.
    const int qi = (sg == 0) ? a : (sg == 1) ? 63 - a : (sg == 2) ? 16 + a : 47 - a;
    const int qbase = qi * 64;
    const int fr = lane & 15, fc = lane >> 4;

    // Q fragments in registers (raw — scale folded into exp2 constant)
    bf16x8 qf[2];
    #pragma unroll
    for (int kh = 0; kh < 2; ++kh)
        qf[kh] = *(const bf16x8*)(Q + (size_t)(qbase + w * 16 + fr) * DMODEL
                                    + h * HD + kh * 32 + fc * 8);

    f32x4 o[4] = {};        // o[fd][r]: d = fd*16 + fc*4 + r, q = fr
    float lsum = 0.f;       // row-sum partial for q-row fr

    auto stage = [&](int buf, int kb2) {
        const int kbase2 = kb2 * 64;
        #pragma unroll
        for (int i = 0; i < 2; ++i) {
            int row = w * 16 + i * 8 + (lane >> 3);
            int gch = (lane & 7) ^ (row & 7);
            gl_lds16(Kb + (size_t)(kbase2 + row) * DMODEL + h * HD + gch * 8,
                     &Ks[buf][(w * 16 + i * 8) * 64]);
            gl_lds16(Vt + (size_t)(h * HD + row) * S_LEN + kbase2 + gch * 8,
                     &Vs[buf][(w * 16 + i * 8) * 64]);
        }
    };

    stage(0, 0);
    __syncthreads();

    int cur = 0;
    for (int kb = 0; kb <= qi; ++kb) {
        if (kb < qi) stage(cur ^ 1, kb + 1);   // prefetch overlaps compute

        // ---- S^T = K Q^T : s[fn][r] = S[q=fr][kv = fn*16 + fc*4 + r] ----
        f32x4 s[4] = {};
        #pragma unroll
        for (int fn = 0; fn < 4; ++fn)
            #pragma unroll
            for (int kh = 0; kh < 2; ++kh) {
                bf16x8 kf = *(const bf16x8*)
                    &Ks[cur][(fn * 16 + fr) * 64 + (((kh * 4 + fc) ^ (fr & 7)) * 8)];
                s[fn] = __builtin_amdgcn_mfma_f32_16x16x32_bf16(kf, qf[kh], s[fn], 0, 0, 0);
            }

        if (kb == qi) {   // causal mask on the diagonal tile: kv > q
            #pragma unroll
            for (int fn = 0; fn < 4; ++fn)
                #pragma unroll
                for (int r = 0; r < 4; ++r)
                    if (fn * 16 + fc * 4 + r > w * 16 + fr) s[fn][r] = -INFINITY;
        }

        // ---- p = exp2(S_raw * log2e/8), in place; scalar lsum ----
        #pragma unroll
        for (int fn = 0; fn < 4; ++fn)
            #pragma unroll
            for (int r = 0; r < 4; ++r) {
                float p = exp2f(s[fn][r] * 0.18033688011112042f);
                lsum += p;
                s[fn][r] = p;
            }

        // ---- O^T += V P^T with permuted k-map: k = 8*fc + 4*(fn&1) + r ----
        #pragma unroll
        for (int kvh = 0; kvh < 2; ++kvh) {
            bf16x8 pa;
            #pragma unroll
            for (int r = 0; r < 4; ++r) {
                pa[r]     = (bf16)s[2 * kvh][r];
                pa[4 + r] = (bf16)s[2 * kvh + 1][r];
            }
            #pragma unroll
            for (int fd = 0; fd < 4; ++fd) {
                const int rowb = (fd * 16 + fr) * 64 + (fc & 1) * 4;
                bf16x4 va = *(const bf16x4*)
                    &Vs[cur][rowb + (((kvh * 4     + (fc >> 1)) ^ (fr & 7)) * 8)];
                bf16x4 vb = *(const bf16x4*)
                    &Vs[cur][rowb + (((kvh * 4 + 2 + (fc >> 1)) ^ (fr & 7)) * 8)];
                bf16x8 vf;
                #pragma unroll
                for (int e = 0; e < 4; ++e) { vf[e] = va[e]; vf[4 + e] = vb[e]; }
                o[fd] = __builtin_amdgcn_mfma_f32_16x16x32_bf16(vf, pa, o[fd], 0, 0, 0);
            }
        }

        __syncthreads();   // drains prefetch (vmcnt) + protects LDS bufs
        cur ^= 1;
    }

    // ---- epilogue: reduce lsum across the 4 fc-lanes of this q-row ----
    lsum += __shfl_xor(lsum, 16, 64);
    lsum += __shfl_xor(lsum, 32, 64);
    const float inv = 1.0f / lsum;

    #pragma unroll
    for (int fd = 0; fd < 4; ++fd) {
        bf16x4 ov;
        #pragma unroll
        for (int r = 0; r < 4; ++r) ov[r] = (bf16)(o[fd][r] * inv);
        *(bf16x4*)(O + (size_t)(qbase + w * 16 + fr) * DMODEL
                     + h * HD + fd * 16 + fc * 4) = ov;
    }
}

// ---------------------------------------------------------------------------
extern "C" void kernel_launch(void* const* d_in, const int* in_sizes, int n_in,
                              void* d_out, int out_size, void* d_ws, size_t ws_size,
                              hipStream_t stream)
{
    const float* x  = (const float*)d_in[0];
    const float* Wq = (const float*)d_in[1];
    const float* Wk = (const float*)d_in[2];
    const float* Wv = (const float*)d_in[3];
    const float* Wo = (const float*)d_in[4];

    const size_t M1 = 1024 * 1024;
    bf16* xb  = (bf16*)d_ws;          // 4M elems
    bf16* wqb = xb  + 4 * M1;         // 1M each
    bf16* wkb = wqb + M1;
    bf16* wvb = wkb + M1;
    bf16* wob = wvb + M1;
    bf16* Qb  = wob + M1;             // 4M
    bf16* Kb  = Qb  + 4 * M1;         // 4M
    bf16* Vt  = Kb  + 4 * M1;         // 4M  (transposed: [DMODEL][S])
    bf16* Ob  = Vt  + 4 * M1;         // 4M

    f32_to_bf16_all<<<4096, 256, 0, stream>>>(x, Wq, Wk, Wv, Wo,
                                              xb, wqb, wkb, wvb, wob);

    gemm_qkv<<<dim3(S_LEN / 128, DMODEL / 128, 3), 256, 0, stream>>>(
        xb, wqb, wkb, wvb, Qb, Kb, Vt);

    attn_mfma<<<dim3((S_LEN / 64) * NH), 256, 0, stream>>>(Qb, Kb, Vt, Ob);

    gemm_out<<<dim3(S_LEN / 128, DMODEL / 128), 256, 0, stream>>>(
        Ob, wob, (float*)d_out);
}